// Round 6
// baseline (879.067 us; speedup 1.0000x reference)
//
#include <hip/hip_runtime.h>

#define T_STEPS 1024
#define BATCH   1024
#define NS      64
#define CPW     16                      // chains per stream (MFMA N dim)
#define NBLK    (BATCH / (2 * CPW))     // 32 blocks, 2 streams per wave
#define TS      ((size_t)BATCH * NS)    // floats per timestep plane

typedef __attribute__((ext_vector_type(8))) __bf16 bf16x8;
typedef __attribute__((ext_vector_type(4))) __bf16 bf16x4;
typedef __attribute__((ext_vector_type(4))) float  f32x4;

// ds_swizzle BitMode xor-16 within each 32-lane group
#define SWZ_XOR16 0x401F
__device__ __forceinline__ float swz16f(float x) {
    return __uint_as_float((unsigned)__builtin_amdgcn_ds_swizzle(
        (int)__float_as_uint(x), SWZ_XOR16));
}

// v10: v9's per-step data path verified correct but latency-serial: of its
// 736 cyc/step only ~160 was work (MFMA 31 + VALU 112 + conflicts 16, from
// MfmaUtil/VALUBusy normalized to 64 active CUs); ~575 cyc was the exposed
// chain mfma->scale->cvt->ds_write->ds_read->mfma at 1 wave/SIMD. v10 runs
// TWO independent 16-chain streams per wave (32 chains/block, 32 blocks) and
// interleaves their steps so each stream's DS/MFMA latency drains under the
// other stream's issue: per pair  MFMA_A, MFMA_B, EPI_A, EPI_B  — A's LDS
// read retires under EPI_B, B's under next MFMA_A. Data path per stream is
// bit-identical to v9 (fragment maps, chunk^c7 swizzle, renorm-every-4,
// __any capture at t==Lc-1).
__global__ __launch_bounds__(64)
__attribute__((amdgpu_waves_per_eu(1, 1)))
void crf_fwd_v10(const float* __restrict__ em,     // [T, B, S]
                 const int*   __restrict__ seqlen, // [B]
                 const float* __restrict__ start,  // [S]
                 const float* __restrict__ stop,   // [S]
                 const float* __restrict__ trans,  // [S, S]
                 float*       __restrict__ out) {  // [B]
    __shared__ __align__(16) char UldsA[CPW * 128];   // stream A: 16 x 64 bf16
    __shared__ __align__(16) char UldsB[CPW * 128];   // stream B

    const int l  = threadIdx.x;
    const int c  = l & 15;
    const int g  = l >> 4;
    const int c7 = c & 7;
    const int obA = blockIdx.x * (2 * CPW) + c;   // stream A chain id
    const int obB = obA + CPW;                    // stream B chain id
    const int LcA = seqlen[obA];
    const int LcB = seqlen[obB];

    // ---- E as bf16 A-fragments (shared by both streams) ----
    bf16x8 ae[4][2];
#pragma unroll
    for (int mt = 0; mt < 4; ++mt)
#pragma unroll
        for (int ks = 0; ks < 2; ++ks) {
            const float* tp = trans + (size_t)(16 * mt + c) * NS + 32 * ks + 8 * g;
            f32x4 t0 = *(const f32x4*)tp;
            f32x4 t1 = *(const f32x4*)(tp + 4);
            bf16x8 a;
            a[0] = (__bf16)__expf(t0[0]); a[1] = (__bf16)__expf(t0[1]);
            a[2] = (__bf16)__expf(t0[2]); a[3] = (__bf16)__expf(t0[3]);
            a[4] = (__bf16)__expf(t1[0]); a[5] = (__bf16)__expf(t1[1]);
            a[6] = (__bf16)__expf(t1[2]); a[7] = (__bf16)__expf(t1[3]);
            ae[mt][ks] = a;
        }

    // ---- exp(stop) per lane (shared; used only in captures) ----
    float es[4][4];
#pragma unroll
    for (int mt = 0; mt < 4; ++mt) {
        f32x4 sv = *(const f32x4*)(stop + 16 * mt + 4 * g);
#pragma unroll
        for (int i = 0; i < 4; ++i) es[mt][i] = __expf(sv[i]);
    }

    // ---- LDS byte offsets (state-chunk XOR c&7 swizzle; same both streams) ----
    char* ubA = (char*)UldsA;
    char* ubB = (char*)UldsB;
    int woff[4], boff[2];
#pragma unroll
    for (int mt = 0; mt < 4; ++mt)
        woff[mt] = c * 128 + ((((2 * mt + (g >> 1)) ^ c7) << 4) | ((g & 1) << 3));
#pragma unroll
    for (int ks = 0; ks < 2; ++ks)
        boff[ks] = c * 128 + (((4 * ks + g) ^ c7) << 4);

    // ---- per-stream em lane base; loads at base + t*TS + 16*mt ----
    const float* empA = em + (size_t)obA * NS + 4 * g;
    const float* empB = em + (size_t)obB * NS + 4 * g;

    f32x4 embA[4][4], embB[4][4];       // [slot][mt] em ring, 4 steps deep
    float uA[4][4], uB[4][4];
    f32x4 accA[4], accB[4];
    bf16x8 bfAA, bfBA, bfAB, bfBB;      // bf{A,B}<stream>
    float mlocA, mlocB, caccA, caccB, invA, invB;

#define CAPT(SF, T_)                                                          \
    do {                                                                      \
        float dv_ = 0.f;                                                      \
        _Pragma("unroll") for (int m_ = 0; m_ < 4; ++m_)                      \
            _Pragma("unroll") for (int i_ = 0; i_ < 4; ++i_)                  \
                dv_ = fmaf(u##SF[m_][i_], es[m_][i_], dv_);                   \
        dv_ += swz16f(dv_);                                                   \
        dv_ += __shfl_xor(dv_, 32, 64);                                       \
        if ((T_) == Lc##SF - 1 && g == 0) out[ob##SF] = __logf(dv_) + cacc##SF; \
    } while (0)

#define WRR(SF)                                                               \
    do {                                                                      \
        bf16x4 q0_, q1_;                                                      \
        q0_[0] = (__bf16)u##SF[0][0]; q0_[1] = (__bf16)u##SF[0][1];           \
        q0_[2] = (__bf16)u##SF[0][2]; q0_[3] = (__bf16)u##SF[0][3];           \
        q1_[0] = (__bf16)u##SF[1][0]; q1_[1] = (__bf16)u##SF[1][1];           \
        q1_[2] = (__bf16)u##SF[1][2]; q1_[3] = (__bf16)u##SF[1][3];           \
        *(bf16x4*)(ub##SF + woff[0]) = q0_;                                   \
        *(bf16x4*)(ub##SF + woff[1]) = q1_;                                   \
        bfA##SF = *(bf16x8*)(ub##SF + boff[0]);                               \
        q0_[0] = (__bf16)u##SF[2][0]; q0_[1] = (__bf16)u##SF[2][1];           \
        q0_[2] = (__bf16)u##SF[2][2]; q0_[3] = (__bf16)u##SF[2][3];           \
        q1_[0] = (__bf16)u##SF[3][0]; q1_[1] = (__bf16)u##SF[3][1];           \
        q1_[2] = (__bf16)u##SF[3][2]; q1_[3] = (__bf16)u##SF[3][3];           \
        *(bf16x4*)(ub##SF + woff[2]) = q0_;                                   \
        *(bf16x4*)(ub##SF + woff[3]) = q1_;                                   \
        bfB##SF = *(bf16x8*)(ub##SF + boff[1]);                               \
    } while (0)

#define MFMAP(SF)                                                             \
    do {                                                                      \
        f32x4 zz_ = {0.f, 0.f, 0.f, 0.f};                                     \
        _Pragma("unroll") for (int m_ = 0; m_ < 4; ++m_)                      \
            acc##SF[m_] = __builtin_amdgcn_mfma_f32_16x16x32_bf16(            \
                ae[m_][0], bfA##SF, zz_, 0, 0, 0);                            \
        _Pragma("unroll") for (int m_ = 0; m_ < 4; ++m_)                      \
            acc##SF[m_] = __builtin_amdgcn_mfma_f32_16x16x32_bf16(            \
                ae[m_][1], bfB##SF, acc##SF[m_], 0, 0, 0);                    \
    } while (0)

#define EPI(SF, T_, SLOT_, RN_, LAST_)                                        \
    do {                                                                      \
        if (RN_) {                                                            \
            float v1_ = fmaxf(mloc##SF, swz16f(mloc##SF));                    \
            float mm_ = fmaxf(v1_, __shfl_xor(v1_, 32, 64));                  \
            mm_ = fmaxf(mm_, 1e-30f);                                         \
            inv##SF = __builtin_amdgcn_rcpf(mm_);                             \
            cacc##SF += __logf(mm_);                                          \
        }                                                                     \
        _Pragma("unroll") for (int m_ = 0; m_ < 4; ++m_)                      \
            _Pragma("unroll") for (int i_ = 0; i_ < 4; ++i_) {                \
                float exv_ = __expf(emb##SF[SLOT_][m_][i_]);                  \
                if (RN_) exv_ *= inv##SF;                                     \
                u##SF[m_][i_] = acc##SF[m_][i_] * exv_;                       \
            }                                                                 \
        {                                                                     \
            size_t tn_ = (size_t)(((T_) + 4 <= T_STEPS - 1) ? (T_) + 4        \
                                                            : T_STEPS - 1);   \
            const float* p_ = emp##SF + tn_ * TS;                             \
            _Pragma("unroll") for (int m_ = 0; m_ < 4; ++m_)                  \
                emb##SF[SLOT_][m_] = *(const f32x4*)(p_ + 16 * m_);           \
        }                                                                     \
        if (__any((T_) == Lc##SF - 1)) CAPT(SF, T_);                          \
        if (LAST_) {                                                          \
            mloc##SF = u##SF[0][0];                                           \
            _Pragma("unroll") for (int m_ = 0; m_ < 4; ++m_)                  \
                _Pragma("unroll") for (int i_ = 0; i_ < 4; ++i_)              \
                    mloc##SF = fmaxf(mloc##SF, u##SF[m_][i_]);                \
        }                                                                     \
        WRR(SF);                                                              \
    } while (0)

#define INIT(SF)                                                              \
    do {                                                                      \
        _Pragma("unroll") for (int S_ = 0; S_ < 4; ++S_)                      \
            _Pragma("unroll") for (int m_ = 0; m_ < 4; ++m_)                  \
                emb##SF[S_][m_] =                                             \
                    *(const f32x4*)(emp##SF + (size_t)S_ * TS + 16 * m_);     \
        _Pragma("unroll") for (int m_ = 0; m_ < 4; ++m_) {                    \
            f32x4 sv_ = *(const f32x4*)(start + 16 * m_ + 4 * g);             \
            _Pragma("unroll") for (int i_ = 0; i_ < 4; ++i_)                  \
                u##SF[m_][i_] = __expf(sv_[i_] + emb##SF[0][m_][i_]);         \
        }                                                                     \
        _Pragma("unroll") for (int m_ = 0; m_ < 4; ++m_)                      \
            emb##SF[0][m_] = *(const f32x4*)(emp##SF + (size_t)4 * TS + 16 * m_); \
        cacc##SF = 0.f; inv##SF = 1.f; (void)inv##SF;                         \
        if (__any(0 == Lc##SF - 1)) CAPT(SF, 0);                              \
        mloc##SF = u##SF[0][0];                                               \
        _Pragma("unroll") for (int m_ = 0; m_ < 4; ++m_)                      \
            _Pragma("unroll") for (int i_ = 0; i_ < 4; ++i_)                  \
                mloc##SF = fmaxf(mloc##SF, u##SF[m_][i_]);                    \
        WRR(SF);                                                              \
    } while (0)

    // interleaved pair: MFMA of both streams first, then both epilogues —
    // each stream's LDS round-trip and MFMA dep chain drain under the other
    // stream's instruction issue.
#define PAIR(T_, SLOT_, RN_, LAST_)                                           \
    do {                                                                      \
        MFMAP(A); MFMAP(B);                                                   \
        EPI(A, T_, SLOT_, RN_, LAST_);                                        \
        EPI(B, T_, SLOT_, RN_, LAST_);                                        \
    } while (0)

    // ---- init (t = 0) ----
    INIT(A);
    INIT(B);

    // ---- main loop: t = 1..1024 (256 groups of 4; step 1024 is inert:
    // captures need t <= 1023, dead columns evolve harmlessly) ----
    for (int grp = 0; grp < 256; ++grp) {
        const int t0_ = 1 + 4 * grp;
        PAIR(t0_ + 0, 1, 1, 0);
        PAIR(t0_ + 1, 2, 0, 0);
        PAIR(t0_ + 2, 3, 0, 0);
        PAIR(t0_ + 3, 0, 0, 1);
    }
}

extern "C" void kernel_launch(void* const* d_in, const int* in_sizes, int n_in,
                              void* d_out, int out_size, void* d_ws, size_t ws_size,
                              hipStream_t stream) {
    const float* em     = (const float*)d_in[0]; // [T, B, S]
    const int*   seqlen = (const int*)  d_in[1]; // [B]
    const float* start  = (const float*)d_in[2]; // [S]
    const float* stop   = (const float*)d_in[3]; // [S]
    const float* trans  = (const float*)d_in[4]; // [S, S]
    float*       out    = (float*)d_out;         // [B]

    crf_fwd_v10<<<NBLK, 64, 0, stream>>>(em, seqlen, start, stop, trans, out);
}

// Round 7
// 527.389 us; speedup vs baseline: 1.6668x; 1.6668x over previous
//
#include <hip/hip_runtime.h>

#define T_STEPS 1024
#define BATCH   1024
#define NS      64
#define CPB     16                      // chains per block (MFMA N dim)
#define NBLK    (BATCH / CPB)           // 64 blocks
#define TS      ((size_t)BATCH * NS)    // floats per timestep plane

typedef __attribute__((ext_vector_type(8))) __bf16 bf16x8;
typedef __attribute__((ext_vector_type(4))) float  f32x4;

// ds_swizzle BitMode xor-16 within each 32-lane group
#define SWZ_XOR16 0x401F
__device__ __forceinline__ float swz16f(float x) {
    return __uint_as_float((unsigned)__builtin_amdgcn_ds_swizzle(
        (int)__float_as_uint(x), SWZ_XOR16));
}

// v11: register-closed MFMA recurrence — no LDS anywhere in the step.
// v9/v10 post-mortem: per-step time is pure critical-path latency (TLP can't
// shorten a serial chain — v10 proved it); the long pole was the LDS
// D-layout -> B-layout shuffle. But the K-dim state ordering is a free
// choice: with phi(32ks+8g+e) = 16*(2ks+(e>>2)) + 4g + (e&3), every B-slot a
// lane must supply IS one of its own D registers:
//     bfA = pack(u[0][0..3], u[1][0..3]),  bfB = pack(u[2][0..3], u[3][0..3])
// (pure same-lane packing). The permutation is compensated in the A-fragment
// gather (prologue only):
//     ae[mt'][ks][e] = exp(trans[16mt'+c][32ks + 16*(e>>2) + 4g + (e&3)])
// Fragment maps (validated end-to-end by v9 passing):
//     A: row=l&15, k=8*(l>>4)+e;  B: col=l&15, k=8*(l>>4)+e;
//     D: col=l&15, row=4*(l>>4)+reg  ->  acc[mt][i] == u[mt][i] (closure).
// Everything else (em ring depth 4, renorm every 4 via cross-g max, __any
// capture at t==Lc-1) is v9's validated path, index-identical.
__global__ __launch_bounds__(64)
void crf_fwd_v11(const float* __restrict__ em,     // [T, B, S]
                 const int*   __restrict__ seqlen, // [B]
                 const float* __restrict__ start,  // [S]
                 const float* __restrict__ stop,   // [S]
                 const float* __restrict__ trans,  // [S, S]
                 float*       __restrict__ out) {  // [B]
    const int l  = threadIdx.x;
    const int c  = l & 15;
    const int g  = l >> 4;
    const int b0 = blockIdx.x * CPB;
    const int Lc = seqlen[b0 + c];

    // ---- E as bf16 A-fragments, phi-compensated gather ----
    bf16x8 ae[4][2];
#pragma unroll
    for (int mt = 0; mt < 4; ++mt)
#pragma unroll
        for (int ks = 0; ks < 2; ++ks) {
            const float* rp = trans + (size_t)(16 * mt + c) * NS + 32 * ks + 4 * g;
            f32x4 t0 = *(const f32x4*)rp;          // e=0..3: col 32ks+4g+i
            f32x4 t1 = *(const f32x4*)(rp + 16);   // e=4..7: col 32ks+16+4g+i
            bf16x8 a;
            a[0] = (__bf16)__expf(t0[0]); a[1] = (__bf16)__expf(t0[1]);
            a[2] = (__bf16)__expf(t0[2]); a[3] = (__bf16)__expf(t0[3]);
            a[4] = (__bf16)__expf(t1[0]); a[5] = (__bf16)__expf(t1[1]);
            a[6] = (__bf16)__expf(t1[2]); a[7] = (__bf16)__expf(t1[3]);
            ae[mt][ks] = a;
        }

    // ---- exp(stop) per lane (captures only) ----
    float es[4][4];
#pragma unroll
    for (int mt = 0; mt < 4; ++mt) {
        f32x4 sv = *(const f32x4*)(stop + 16 * mt + 4 * g);
#pragma unroll
        for (int i = 0; i < 4; ++i) es[mt][i] = __expf(sv[i]);
    }

    // ---- em lane base; loads at base + t*TS + 16*mt ----
    const float* emp = em + (size_t)(b0 + c) * NS + 4 * g;

    f32x4 emb[4][4];                    // [slot][mt], ring 4 steps deep
    float u[4][4];
    f32x4 acc[4];
    bf16x8 bfA, bfB;
    float mloc, cacc, inv;

#define CAPT(T_)                                                              \
    do {                                                                      \
        float dv_ = 0.f;                                                      \
        _Pragma("unroll") for (int m_ = 0; m_ < 4; ++m_)                      \
            _Pragma("unroll") for (int i_ = 0; i_ < 4; ++i_)                  \
                dv_ = fmaf(u[m_][i_], es[m_][i_], dv_);                       \
        dv_ += swz16f(dv_);                                                   \
        dv_ += __shfl_xor(dv_, 32, 64);                                       \
        if ((T_) == Lc - 1 && g == 0) out[b0 + c] = __logf(dv_) + cacc;       \
    } while (0)

    // same-lane D->B repack: bfA = u[0..1], bfB = u[2..3] (bf16)
#define PACKB()                                                               \
    do {                                                                      \
        bf16x8 xa_, xb_;                                                      \
        xa_[0] = (__bf16)u[0][0]; xa_[1] = (__bf16)u[0][1];                   \
        xa_[2] = (__bf16)u[0][2]; xa_[3] = (__bf16)u[0][3];                   \
        xa_[4] = (__bf16)u[1][0]; xa_[5] = (__bf16)u[1][1];                   \
        xa_[6] = (__bf16)u[1][2]; xa_[7] = (__bf16)u[1][3];                   \
        xb_[0] = (__bf16)u[2][0]; xb_[1] = (__bf16)u[2][1];                   \
        xb_[2] = (__bf16)u[2][2]; xb_[3] = (__bf16)u[2][3];                   \
        xb_[4] = (__bf16)u[3][0]; xb_[5] = (__bf16)u[3][1];                   \
        xb_[6] = (__bf16)u[3][2]; xb_[7] = (__bf16)u[3][3];                   \
        bfA = xa_; bfB = xb_;                                                 \
    } while (0)

#define STEP(T_, SLOT_, RN_, LAST_)                                           \
    do {                                                                      \
        f32x4 zz_ = {0.f, 0.f, 0.f, 0.f};                                     \
        _Pragma("unroll") for (int m_ = 0; m_ < 4; ++m_)                      \
            acc[m_] = __builtin_amdgcn_mfma_f32_16x16x32_bf16(                \
                ae[m_][0], bfA, zz_, 0, 0, 0);                                \
        _Pragma("unroll") for (int m_ = 0; m_ < 4; ++m_)                      \
            acc[m_] = __builtin_amdgcn_mfma_f32_16x16x32_bf16(                \
                ae[m_][1], bfB, acc[m_], 0, 0, 0);                            \
        if (RN_) {                                                            \
            float v1_ = fmaxf(mloc, swz16f(mloc));                            \
            float mm_ = fmaxf(v1_, __shfl_xor(v1_, 32, 64));                  \
            mm_ = fmaxf(mm_, 1e-30f);                                         \
            inv = __builtin_amdgcn_rcpf(mm_);                                 \
            cacc += __logf(mm_);                                              \
        }                                                                     \
        _Pragma("unroll") for (int m_ = 0; m_ < 4; ++m_)                      \
            _Pragma("unroll") for (int i_ = 0; i_ < 4; ++i_) {                \
                float exv_ = __expf(emb[SLOT_][m_][i_]);                      \
                if (RN_) exv_ *= inv;                                         \
                u[m_][i_] = acc[m_][i_] * exv_;                               \
            }                                                                 \
        {   /* prefetch em for T_+4 (clamped; dead reads harmless) */         \
            size_t tn_ = (size_t)(((T_) + 4 <= T_STEPS - 1) ? (T_) + 4        \
                                                            : T_STEPS - 1);   \
            const float* p_ = emp + tn_ * TS;                                 \
            _Pragma("unroll") for (int m_ = 0; m_ < 4; ++m_)                  \
                emb[SLOT_][m_] = *(const f32x4*)(p_ + 16 * m_);               \
        }                                                                     \
        if (__any((T_) == Lc - 1)) CAPT(T_);                                  \
        if (LAST_) {                                                          \
            mloc = u[0][0];                                                   \
            _Pragma("unroll") for (int m_ = 0; m_ < 4; ++m_)                  \
                _Pragma("unroll") for (int i_ = 0; i_ < 4; ++i_)              \
                    mloc = fmaxf(mloc, u[m_][i_]);                            \
        }                                                                     \
        PACKB();                                                              \
    } while (0)

    // ---- init (t = 0) ----
#pragma unroll
    for (int S = 0; S < 4; ++S)
#pragma unroll
        for (int mt = 0; mt < 4; ++mt)
            emb[S][mt] = *(const f32x4*)(emp + (size_t)S * TS + 16 * mt);
#pragma unroll
    for (int mt = 0; mt < 4; ++mt) {
        f32x4 sv = *(const f32x4*)(start + 16 * mt + 4 * g);
#pragma unroll
        for (int i = 0; i < 4; ++i)
            u[mt][i] = __expf(sv[i] + emb[0][mt][i]);
    }
#pragma unroll
    for (int mt = 0; mt < 4; ++mt)       // slot 0 -> em[4]
        emb[0][mt] = *(const f32x4*)(emp + (size_t)4 * TS + 16 * mt);

    cacc = 0.f; inv = 1.f; (void)inv;
    if (__any(0 == Lc - 1)) CAPT(0);

    mloc = u[0][0];
#pragma unroll
    for (int mt = 0; mt < 4; ++mt)
#pragma unroll
        for (int i = 0; i < 4; ++i) mloc = fmaxf(mloc, u[mt][i]);

    PACKB();

    // ---- main loop: t = 1..1024 (256 groups of 4; step 1024 is inert:
    // captures need t <= 1023, dead columns evolve harmlessly) ----
    for (int grp = 0; grp < 256; ++grp) {
        const int t0_ = 1 + 4 * grp;
        STEP(t0_ + 0, 1, 1, 0);
        STEP(t0_ + 1, 2, 0, 0);
        STEP(t0_ + 2, 3, 0, 0);
        STEP(t0_ + 3, 0, 0, 1);
    }
}

extern "C" void kernel_launch(void* const* d_in, const int* in_sizes, int n_in,
                              void* d_out, int out_size, void* d_ws, size_t ws_size,
                              hipStream_t stream) {
    const float* em     = (const float*)d_in[0]; // [T, B, S]
    const int*   seqlen = (const int*)  d_in[1]; // [B]
    const float* start  = (const float*)d_in[2]; // [S]
    const float* stop   = (const float*)d_in[3]; // [S]
    const float* trans  = (const float*)d_in[4]; // [S, S]
    float*       out    = (float*)d_out;         // [B]

    crf_fwd_v11<<<NBLK, 64, 0, stream>>>(em, seqlen, start, stop, trans, out);
}